// Round 12
// baseline (229.762 us; speedup 1.0000x reference)
//
#include <hip/hip_runtime.h>

// GCN 2-layer, N=100000, E=3200000, 13 -> 32 -> 16.
// v11 = v9 (213.9us best) with binB half-step: keep LDS wbuf staging (hist &
// scatter read LDS), drop sorted_ -- scatter stores go directly into the
// bucket's dense 32KB srcs window (stores don't stall; L2 write-combines).
// LDS 77KB -> 42KB: 3 blocks/CU. binA/agg/gemm12 unchanged.

constexpr int N_NODES = 100000;
constexpr int N_EDGES = 3200000;
constexpr int IN_CH  = 13;
constexpr int HID_CH = 32;
constexpr int LAT_CH = 16;

constexpr int NPB  = 256;                          // nodes per bucket (dst>>8)
constexpr int NBKT = (N_NODES + NPB - 1) / NPB;    // 391
constexpr int BCAP = 8960;                         // mean 8192, sd ~90 -> +8.5 sigma
constexpr int TILE = 4096;                         // edges per binA block (8/thread)

__global__ __launch_bounds__(512) void k_zero_bcur(int* __restrict__ bcur) {
    int i = threadIdx.x;
    if (i < NBKT) bcur[i] = 0;
}

// bin edges into coarse bucket regions; packed word = (dst&255)<<17 | src.
// One pass over the edge list: 8 edges/thread staged in registers (int4 x2).
__global__ __launch_bounds__(512) void k_binA(const int* __restrict__ src,
                                              const int* __restrict__ dst,
                                              int* __restrict__ bcur,
                                              int* __restrict__ buckets) {
    __shared__ int h[NBKT], st[NBKT], cur[NBKT];
    int tid = threadIdx.x;
    for (int i = tid; i < NBKT; i += 512) h[i] = 0;
    __syncthreads();
    int base8 = blockIdx.x * TILE + tid * 8;       // TILE = 512*8; groups never split
    int d[8], s[8];
    bool have = base8 < N_EDGES;
    if (have) {
        const int4* dp = (const int4*)(dst + base8);
        const int4* sp = (const int4*)(src + base8);
        int4 d0 = dp[0], d1 = dp[1];
        int4 s0 = sp[0], s1 = sp[1];
        d[0]=d0.x; d[1]=d0.y; d[2]=d0.z; d[3]=d0.w;
        d[4]=d1.x; d[5]=d1.y; d[6]=d1.z; d[7]=d1.w;
        s[0]=s0.x; s[1]=s0.y; s[2]=s0.z; s[3]=s0.w;
        s[4]=s1.x; s[5]=s1.y; s[6]=s1.z; s[7]=s1.w;
#pragma unroll
        for (int j = 0; j < 8; ++j) atomicAdd(&h[d[j] >> 8], 1);
    }
    __syncthreads();
    for (int i = tid; i < NBKT; i += 512) {
        int c = h[i];
        st[i] = c > 0 ? atomicAdd(&bcur[i], c) : 0;
        cur[i] = 0;
    }
    __syncthreads();
    if (have) {
#pragma unroll
        for (int j = 0; j < 8; ++j) {
            int b = d[j] >> 8;
            int r = atomicAdd(&cur[b], 1);
            buckets[b * BCAP + st[b] + r] = s[j] | ((d[j] & 255) << 17);
        }
    }
}

// per-bucket counting sort with LDS wbuf staging and direct-global scatter:
//  - local scan of bcur gives CSR base (no scanTop kernel)
//  - stage bucket words in LDS (1 coalesced global read)
//  - LDS hist[256] -> dis/off emission -> LDS scan
//  - scatter: wbuf (LDS) -> LDS cursor atomic -> direct 4B store into the
//    bucket's dense srcs window (fire-and-forget; L2 write-combines)
//  - fused xn emission for the bucket's 256 nodes
__global__ __launch_bounds__(512) void k_binB(const int* __restrict__ bcur,
                                              const int* __restrict__ buckets,
                                              const float* __restrict__ x,
                                              int* __restrict__ off,
                                              float* __restrict__ dis,
                                              int* __restrict__ srcs,
                                              float* __restrict__ xn) {
    __shared__ int wbuf[BCAP];     // staged bucket words (35KB)
    __shared__ int h[NPB], ex[NPB], curso[NPB];
    __shared__ int sv[512];        // top-level scan buffer
    __shared__ float sdis[NPB];
    int b = blockIdx.x, tid = threadIdx.x;

    // local top scan (inclusive over 512 slots, zeros beyond NBKT)
    sv[tid] = (tid < NBKT) ? bcur[tid] : 0;
    __syncthreads();
    for (int d = 1; d < 512; d <<= 1) {
        int a = sv[tid];
        int u = (tid >= d) ? sv[tid - d] : 0;
        __syncthreads();
        sv[tid] = a + u;
        __syncthreads();
    }
    int base = (b > 0) ? sv[b - 1] : 0;     // exclusive prefix for bucket b
    int cntb = bcur[b];
    if (cntb > BCAP) cntb = BCAP;
    const int* bw = buckets + b * BCAP;

    for (int i = tid; i < cntb; i += 512) wbuf[i] = bw[i];
    if (tid < NPB) h[tid] = 0;
    __syncthreads();
    for (int i = tid; i < cntb; i += 512) atomicAdd(&h[wbuf[i] >> 17], 1);
    __syncthreads();
    int node0 = b * NPB;
    if (tid < NPB) {
        int node = node0 + tid;
        float dv = rsqrtf((float)(h[tid] + 1));   // +1 self-loop
        sdis[tid] = dv;
        if (node < N_NODES) dis[node] = dv;
        ex[tid] = h[tid];
    }
    __syncthreads();
    for (int d = 1; d < NPB; d <<= 1) {    // inclusive scan over 256
        int a = 0, u = 0;
        if (tid < NPB) a = ex[tid];
        if (tid >= d && tid < NPB) u = ex[tid - d];
        __syncthreads();
        if (tid < NPB) ex[tid] = a + u;
        __syncthreads();
    }
    if (tid < NPB) {
        int excl = ex[tid] - h[tid];
        int node = node0 + tid;
        if (node < N_NODES) off[node] = base + excl;
        curso[tid] = excl;
    }
    if (b == 0 && tid == 0) off[N_NODES] = N_EDGES;
    __syncthreads();
    int* srcw = srcs + base;               // this bucket's dense output window
    for (int i = tid; i < cntb; i += 512) {
        int w = wbuf[i];                   // LDS read (fast)
        int r = atomicAdd(&curso[w >> 17], 1);
        srcw[r] = w & 131071;              // non-blocking global store
    }
    // fused xn emission for this bucket's nodes
    for (int i = tid; i < NPB * 16; i += 512) {
        int nl = i >> 4, c = i & 15;
        int node = node0 + nl;
        if (node < N_NODES)
            xn[node * 16 + c] = (c < IN_CH) ? x[node * IN_CH + c] * sdis[nl] : 0.f;
    }
}

// 4 nodes per wave: 16 lanes/node = 4 edge slots x 4 channel-quads, dual
// window (2 float4 gathers in flight/lane), srcs prefetched one window ahead.
// outv[d*16+ch] = dis[d] * (sum_edges vin[s*16+ch] + vin[d*16+ch]) (+ bias)
__global__ __launch_bounds__(256) void k_agg(const int* __restrict__ off,
                                             const int* __restrict__ srcs,
                                             const float* __restrict__ dis,
                                             const float* __restrict__ vin,
                                             const float* __restrict__ bias,  // may be null
                                             float* __restrict__ outv) {
    int wave = (blockIdx.x * 256 + threadIdx.x) >> 6;
    int lane = threadIdx.x & 63;
    int q    = lane & 3;           // channel quad: floats q*4 .. q*4+3
    int esub = (lane >> 2) & 3;    // edge slot 0..3 (and +4 for second window)
    int nsub = lane >> 4;          // node sub-index 0..3
    int node = wave * 4 + nsub;
    bool valid = node < N_NODES;
    int beg = valid ? off[node] : 0;
    int end = valid ? off[node + 1] : 0;

    float ax = 0.f, ay = 0.f, az = 0.f, aw = 0.f;
    int k1 = beg + esub;
    int k2 = k1 + 4;
    int s1 = (k1 < end) ? srcs[k1] : -1;
    int s2 = (k2 < end) ? srcs[k2] : -1;
    for (int kb = beg; kb < end; kb += 8) {
        int kn = kb + 8 + esub;
        int sn1 = (kn < end)     ? srcs[kn]     : -1;   // prefetch next window
        int sn2 = (kn + 4 < end) ? srcs[kn + 4] : -1;
        float4 v1, v2;
        v1.x = v1.y = v1.z = v1.w = 0.f;
        v2.x = v2.y = v2.z = v2.w = 0.f;
        if (s1 >= 0) v1 = *((const float4*)(vin + (size_t)s1 * 16) + q);
        if (s2 >= 0) v2 = *((const float4*)(vin + (size_t)s2 * 16) + q);
        ax += v1.x + v2.x;
        ay += v1.y + v2.y;
        az += v1.z + v2.z;
        aw += v1.w + v2.w;
        s1 = sn1; s2 = sn2;
    }
#pragma unroll
    for (int m = 4; m <= 8; m <<= 1) {         // reduce over esub (lane bits 2..3)
        ax += __shfl_xor(ax, m);
        ay += __shfl_xor(ay, m);
        az += __shfl_xor(az, m);
        aw += __shfl_xor(aw, m);
    }
    if (esub == 0 && valid) {                  // 4 nodes x 4 quads = 16 store lanes
        const float4 self = *((const float4*)(vin + (size_t)node * 16) + q);
        float d = dis[node];
        float4 r;
        r.x = d * (ax + self.x);
        r.y = d * (ay + self.y);
        r.z = d * (az + self.z);
        r.w = d * (aw + self.w);
        if (bias) {
            const float4 bq = ((const float4*)bias)[q];
            r.x += bq.x; r.y += bq.y; r.z += bq.z; r.w += bq.w;
        }
        *((float4*)(outv + (size_t)node * 16) + q) = r;
    }
}

// fused: hwn = (relu(s1 @ W1 + b1) @ W2) * dis   (per node, through LDS)
__global__ __launch_bounds__(256) void k_gemm12(const float* __restrict__ s1,
                                                const float* __restrict__ W1,
                                                const float* __restrict__ b1,
                                                const float* __restrict__ W2,
                                                const float* __restrict__ dis,
                                                float* __restrict__ hwn) {
    __shared__ float sW1[IN_CH * HID_CH];
    __shared__ float sW2[HID_CH * LAT_CH];
    __shared__ float sr[8][HID_CH + 1];
    int tid = threadIdx.x;
    for (int i = tid; i < IN_CH * HID_CH; i += 256) sW1[i] = W1[i];
    for (int i = tid; i < HID_CH * LAT_CH; i += 256) sW2[i] = W2[i];
    __syncthreads();
    int nl = tid >> 5, c1 = tid & 31;
    int node = blockIdx.x * 8 + nl;
    float r = 0.f;
    if (node < N_NODES) {
        float acc = b1[c1];
#pragma unroll
        for (int k = 0; k < IN_CH; ++k)
            acc += s1[node * 16 + k] * sW1[k * HID_CH + c1];
        r = acc > 0.f ? acc : 0.f;   // ReLU
    }
    sr[nl][c1] = r;
    __syncthreads();
    if (tid < 128) {
        int nl2 = tid >> 4, c2 = tid & 15;
        int node2 = blockIdx.x * 8 + nl2;
        if (node2 < N_NODES) {
            float acc = 0.f;
#pragma unroll
            for (int k = 0; k < HID_CH; ++k)
                acc += sr[nl2][k] * sW2[k * LAT_CH + c2];
            hwn[node2 * 16 + c2] = acc * dis[node2];
        }
    }
}

extern "C" void kernel_launch(void* const* d_in, const int* in_sizes, int n_in,
                              void* d_out, int out_size, void* d_ws, size_t ws_size,
                              hipStream_t stream) {
    const float* x  = (const float*)d_in[0];
    const int*   ei = (const int*)d_in[1];
    const float* W1 = (const float*)d_in[2];
    const float* b1 = (const float*)d_in[3];
    const float* W2 = (const float*)d_in[4];
    const float* b2 = (const float*)d_in[5];
    float* out = (float*)d_out;

    const int* src = ei;
    const int* dst = ei + N_EDGES;

    // ws layout (bytes):
    //   bcur[391] @ 0 (pad 4096) | off[N+1] @ 4096 | dis[N] @ 404160
    //   srcs[E]   @ 804160 (12.8MB)
    //   buckets   @ 13604160 (391*8960*4 = 14,013,440 -> ends 27,617,600)
    //   s1        @ 20004160 (inside buckets; written post-binB, buckets dead)
    //   xn        @ 27617600 (6.4MB, own region: binB writes it while buckets live)
    //   hwn aliases xn (xn dead after first k_agg)
    char* ws = (char*)d_ws;
    int*   bcur    = (int*)(ws);
    int*   off     = (int*)(ws + 4096);
    float* dis     = (float*)(ws + 404160);
    int*   srcs    = (int*)(ws + 804160);
    int*   buckets = (int*)(ws + 13604160);
    float* s1      = (float*)(ws + 20004160);
    float* xn      = (float*)(ws + 27617600);
    float* hwn     = xn;  // xn dead after first k_agg

    const int NB_A  = (N_EDGES + TILE - 1) / TILE;      // 782
    const int NB_W  = (N_NODES + 15) / 16;              // 4 nodes/wave, 4 waves/block
    const int NB_G  = (N_NODES + 7) / 8;

    k_zero_bcur<<<1,    512, 0, stream>>>(bcur);
    k_binA     <<<NB_A, 512, 0, stream>>>(src, dst, bcur, buckets);
    k_binB     <<<NBKT, 512, 0, stream>>>(bcur, buckets, x, off, dis, srcs, xn);
    k_agg      <<<NB_W,  256, 0, stream>>>(off, srcs, dis, xn, nullptr, s1);
    k_gemm12   <<<NB_G,  256, 0, stream>>>(s1, W1, b1, W2, dis, hwn);
    k_agg      <<<NB_W,  256, 0, stream>>>(off, srcs, dis, hwn, b2, out);
}

// Round 13
// 217.071 us; speedup vs baseline: 1.0585x; 1.0585x over previous
//
#include <hip/hip_runtime.h>

// GCN 2-layer, N=100000, E=3200000, 13 -> 32 -> 16.
// v12 = v9 structure (213.9us best) + rank-from-histogram in both bin kernels:
// the hist atomicAdd's return value IS the local rank, so scatter passes have
// zero atomics. binA drops cur[]; binB loads bucket words to REGISTERS once
// (18 fixed-unrolled slots), drops wbuf (35KB LDS freed -> 4 blocks/CU).
// sorted_ staging + coalesced srcs write retained (v10/v11 proved necessary).

constexpr int N_NODES = 100000;
constexpr int N_EDGES = 3200000;
constexpr int IN_CH  = 13;
constexpr int HID_CH = 32;
constexpr int LAT_CH = 16;

constexpr int NPB  = 256;                          // nodes per bucket (dst>>8)
constexpr int NBKT = (N_NODES + NPB - 1) / NPB;    // 391
constexpr int BCAP = 8960;                         // mean 8192, sd ~90 -> +8.5 sigma
constexpr int TILE = 4096;                         // edges per binA block (8/thread)
constexpr int BJ   = (BCAP + 511) / 512;           // 18 register word slots in binB

__global__ __launch_bounds__(512) void k_zero_bcur(int* __restrict__ bcur) {
    int i = threadIdx.x;
    if (i < NBKT) bcur[i] = 0;
}

// bin edges into coarse bucket regions; packed word = (dst&255)<<17 | src.
// One edge-list pass; hist atomic returns local rank -> scatter is atomic-free.
__global__ __launch_bounds__(512) void k_binA(const int* __restrict__ src,
                                              const int* __restrict__ dst,
                                              int* __restrict__ bcur,
                                              int* __restrict__ buckets) {
    __shared__ int h[NBKT], st[NBKT];
    int tid = threadIdx.x;
    for (int i = tid; i < NBKT; i += 512) h[i] = 0;
    __syncthreads();
    int base8 = blockIdx.x * TILE + tid * 8;       // TILE = 512*8; groups never split
    int d[8], s[8], r[8];
    bool have = base8 < N_EDGES;
    if (have) {
        const int4* dp = (const int4*)(dst + base8);
        const int4* sp = (const int4*)(src + base8);
        int4 d0 = dp[0], d1 = dp[1];
        int4 s0 = sp[0], s1 = sp[1];
        d[0]=d0.x; d[1]=d0.y; d[2]=d0.z; d[3]=d0.w;
        d[4]=d1.x; d[5]=d1.y; d[6]=d1.z; d[7]=d1.w;
        s[0]=s0.x; s[1]=s0.y; s[2]=s0.z; s[3]=s0.w;
        s[4]=s1.x; s[5]=s1.y; s[6]=s1.z; s[7]=s1.w;
#pragma unroll
        for (int j = 0; j < 8; ++j) r[j] = atomicAdd(&h[d[j] >> 8], 1);  // rank!
    }
    __syncthreads();
    for (int i = tid; i < NBKT; i += 512) {
        int c = h[i];
        st[i] = c > 0 ? atomicAdd(&bcur[i], c) : 0;
    }
    __syncthreads();
    if (have) {
#pragma unroll
        for (int j = 0; j < 8; ++j) {
            int b = d[j] >> 8;
            buckets[b * BCAP + st[b] + r[j]] = s[j] | ((d[j] & 255) << 17);
        }
    }
}

// per-bucket counting sort, register-resident words + rank-from-hist:
//  - local scan of bcur gives CSR base
//  - words loaded ONCE global->registers (coalesced, 18 static slots)
//  - hist atomic returns rank; scatter to sorted_ is atomic-free
//  - coalesced srcs write; fused dis/off/xn emission
__global__ __launch_bounds__(512) void k_binB(const int* __restrict__ bcur,
                                              const int* __restrict__ buckets,
                                              const float* __restrict__ x,
                                              int* __restrict__ off,
                                              float* __restrict__ dis,
                                              int* __restrict__ srcs,
                                              float* __restrict__ xn) {
    __shared__ int sorted_[BCAP];  // sorted src ids (35KB)
    __shared__ int h[NPB], ex[NPB];
    __shared__ int sv[512];        // top-level scan buffer
    __shared__ float sdis[NPB];
    int b = blockIdx.x, tid = threadIdx.x;

    // local top scan (inclusive over 512 slots, zeros beyond NBKT)
    sv[tid] = (tid < NBKT) ? bcur[tid] : 0;
    __syncthreads();
    for (int d = 1; d < 512; d <<= 1) {
        int a = sv[tid];
        int u = (tid >= d) ? sv[tid - d] : 0;
        __syncthreads();
        sv[tid] = a + u;
        __syncthreads();
    }
    int base = (b > 0) ? sv[b - 1] : 0;     // exclusive prefix for bucket b
    int cntb = bcur[b];
    if (cntb > BCAP) cntb = BCAP;
    const int* bw = buckets + b * BCAP;

    if (tid < NPB) h[tid] = 0;
    __syncthreads();
    int wreg[BJ], rreg[BJ];
#pragma unroll
    for (int j = 0; j < BJ; ++j) {          // global->reg load + hist (rank kept)
        int i = tid + j * 512;
        if (i < cntb) {
            int w = bw[i];
            wreg[j] = w;
            rreg[j] = atomicAdd(&h[w >> 17], 1);
        } else {
            wreg[j] = -1; rreg[j] = 0;
        }
    }
    __syncthreads();
    int node0 = b * NPB;
    if (tid < NPB) {
        int node = node0 + tid;
        float dv = rsqrtf((float)(h[tid] + 1));   // +1 self-loop
        sdis[tid] = dv;
        if (node < N_NODES) dis[node] = dv;
        ex[tid] = h[tid];
    }
    __syncthreads();
    for (int d = 1; d < NPB; d <<= 1) {    // inclusive scan over 256
        int a = 0, u = 0;
        if (tid < NPB) a = ex[tid];
        if (tid >= d && tid < NPB) u = ex[tid - d];
        __syncthreads();
        if (tid < NPB) ex[tid] = a + u;
        __syncthreads();
    }
    if (tid < NPB) {
        int excl = ex[tid] - h[tid];
        int node = node0 + tid;
        if (node < N_NODES) off[node] = base + excl;
        ex[tid] = excl;                    // reuse ex[] as exclusive base
    }
    if (b == 0 && tid == 0) off[N_NODES] = N_EDGES;
    __syncthreads();
#pragma unroll
    for (int j = 0; j < BJ; ++j) {         // atomic-free scatter to LDS
        int w = wreg[j];
        if (w >= 0) sorted_[ex[w >> 17] + rreg[j]] = w & 131071;
    }
    __syncthreads();
    for (int i = tid; i < cntb; i += 512) srcs[base + i] = sorted_[i];
    // fused xn emission for this bucket's nodes
    for (int i = tid; i < NPB * 16; i += 512) {
        int nl = i >> 4, c = i & 15;
        int node = node0 + nl;
        if (node < N_NODES)
            xn[node * 16 + c] = (c < IN_CH) ? x[node * IN_CH + c] * sdis[nl] : 0.f;
    }
}

// 4 nodes per wave: 16 lanes/node = 4 edge slots x 4 channel-quads, dual
// window (2 float4 gathers in flight/lane), srcs prefetched one window ahead.
// outv[d*16+ch] = dis[d] * (sum_edges vin[s*16+ch] + vin[d*16+ch]) (+ bias)
__global__ __launch_bounds__(256) void k_agg(const int* __restrict__ off,
                                             const int* __restrict__ srcs,
                                             const float* __restrict__ dis,
                                             const float* __restrict__ vin,
                                             const float* __restrict__ bias,  // may be null
                                             float* __restrict__ outv) {
    int wave = (blockIdx.x * 256 + threadIdx.x) >> 6;
    int lane = threadIdx.x & 63;
    int q    = lane & 3;           // channel quad: floats q*4 .. q*4+3
    int esub = (lane >> 2) & 3;    // edge slot 0..3 (and +4 for second window)
    int nsub = lane >> 4;          // node sub-index 0..3
    int node = wave * 4 + nsub;
    bool valid = node < N_NODES;
    int beg = valid ? off[node] : 0;
    int end = valid ? off[node + 1] : 0;

    float ax = 0.f, ay = 0.f, az = 0.f, aw = 0.f;
    int k1 = beg + esub;
    int k2 = k1 + 4;
    int s1 = (k1 < end) ? srcs[k1] : -1;
    int s2 = (k2 < end) ? srcs[k2] : -1;
    for (int kb = beg; kb < end; kb += 8) {
        int kn = kb + 8 + esub;
        int sn1 = (kn < end)     ? srcs[kn]     : -1;   // prefetch next window
        int sn2 = (kn + 4 < end) ? srcs[kn + 4] : -1;
        float4 v1, v2;
        v1.x = v1.y = v1.z = v1.w = 0.f;
        v2.x = v2.y = v2.z = v2.w = 0.f;
        if (s1 >= 0) v1 = *((const float4*)(vin + (size_t)s1 * 16) + q);
        if (s2 >= 0) v2 = *((const float4*)(vin + (size_t)s2 * 16) + q);
        ax += v1.x + v2.x;
        ay += v1.y + v2.y;
        az += v1.z + v2.z;
        aw += v1.w + v2.w;
        s1 = sn1; s2 = sn2;
    }
#pragma unroll
    for (int m = 4; m <= 8; m <<= 1) {         // reduce over esub (lane bits 2..3)
        ax += __shfl_xor(ax, m);
        ay += __shfl_xor(ay, m);
        az += __shfl_xor(az, m);
        aw += __shfl_xor(aw, m);
    }
    if (esub == 0 && valid) {                  // 4 nodes x 4 quads = 16 store lanes
        const float4 self = *((const float4*)(vin + (size_t)node * 16) + q);
        float d = dis[node];
        float4 r;
        r.x = d * (ax + self.x);
        r.y = d * (ay + self.y);
        r.z = d * (az + self.z);
        r.w = d * (aw + self.w);
        if (bias) {
            const float4 bq = ((const float4*)bias)[q];
            r.x += bq.x; r.y += bq.y; r.z += bq.z; r.w += bq.w;
        }
        *((float4*)(outv + (size_t)node * 16) + q) = r;
    }
}

// fused: hwn = (relu(s1 @ W1 + b1) @ W2) * dis   (per node, through LDS)
__global__ __launch_bounds__(256) void k_gemm12(const float* __restrict__ s1,
                                                const float* __restrict__ W1,
                                                const float* __restrict__ b1,
                                                const float* __restrict__ W2,
                                                const float* __restrict__ dis,
                                                float* __restrict__ hwn) {
    __shared__ float sW1[IN_CH * HID_CH];
    __shared__ float sW2[HID_CH * LAT_CH];
    __shared__ float sr[8][HID_CH + 1];
    int tid = threadIdx.x;
    for (int i = tid; i < IN_CH * HID_CH; i += 256) sW1[i] = W1[i];
    for (int i = tid; i < HID_CH * LAT_CH; i += 256) sW2[i] = W2[i];
    __syncthreads();
    int nl = tid >> 5, c1 = tid & 31;
    int node = blockIdx.x * 8 + nl;
    float r = 0.f;
    if (node < N_NODES) {
        float acc = b1[c1];
#pragma unroll
        for (int k = 0; k < IN_CH; ++k)
            acc += s1[node * 16 + k] * sW1[k * HID_CH + c1];
        r = acc > 0.f ? acc : 0.f;   // ReLU
    }
    sr[nl][c1] = r;
    __syncthreads();
    if (tid < 128) {
        int nl2 = tid >> 4, c2 = tid & 15;
        int node2 = blockIdx.x * 8 + nl2;
        if (node2 < N_NODES) {
            float acc = 0.f;
#pragma unroll
            for (int k = 0; k < HID_CH; ++k)
                acc += sr[nl2][k] * sW2[k * LAT_CH + c2];
            hwn[node2 * 16 + c2] = acc * dis[node2];
        }
    }
}

extern "C" void kernel_launch(void* const* d_in, const int* in_sizes, int n_in,
                              void* d_out, int out_size, void* d_ws, size_t ws_size,
                              hipStream_t stream) {
    const float* x  = (const float*)d_in[0];
    const int*   ei = (const int*)d_in[1];
    const float* W1 = (const float*)d_in[2];
    const float* b1 = (const float*)d_in[3];
    const float* W2 = (const float*)d_in[4];
    const float* b2 = (const float*)d_in[5];
    float* out = (float*)d_out;

    const int* src = ei;
    const int* dst = ei + N_EDGES;

    // ws layout (bytes):
    //   bcur[391] @ 0 (pad 4096) | off[N+1] @ 4096 | dis[N] @ 404160
    //   srcs[E]   @ 804160 (12.8MB)
    //   buckets   @ 13604160 (391*8960*4 = 14,013,440 -> ends 27,617,600)
    //   s1        @ 20004160 (inside buckets; written post-binB, buckets dead)
    //   xn        @ 27617600 (6.4MB, own region: binB writes it while buckets live)
    //   hwn aliases xn (xn dead after first k_agg)
    char* ws = (char*)d_ws;
    int*   bcur    = (int*)(ws);
    int*   off     = (int*)(ws + 4096);
    float* dis     = (float*)(ws + 404160);
    int*   srcs    = (int*)(ws + 804160);
    int*   buckets = (int*)(ws + 13604160);
    float* s1      = (float*)(ws + 20004160);
    float* xn      = (float*)(ws + 27617600);
    float* hwn     = xn;  // xn dead after first k_agg

    const int NB_A  = (N_EDGES + TILE - 1) / TILE;      // 782
    const int NB_W  = (N_NODES + 15) / 16;              // 4 nodes/wave, 4 waves/block
    const int NB_G  = (N_NODES + 7) / 8;

    k_zero_bcur<<<1,    512, 0, stream>>>(bcur);
    k_binA     <<<NB_A, 512, 0, stream>>>(src, dst, bcur, buckets);
    k_binB     <<<NBKT, 512, 0, stream>>>(bcur, buckets, x, off, dis, srcs, xn);
    k_agg      <<<NB_W,  256, 0, stream>>>(off, srcs, dis, xn, nullptr, s1);
    k_gemm12   <<<NB_G,  256, 0, stream>>>(s1, W1, b1, W2, dis, hwn);
    k_agg      <<<NB_W,  256, 0, stream>>>(off, srcs, dis, hwn, b2, out);
}

// Round 14
// 205.655 us; speedup vs baseline: 1.1172x; 1.0555x over previous
//
#include <hip/hip_runtime.h>

// GCN 2-layer, N=100000, E=3200000, 13 -> 32 -> 16.
// v13 = v9 (213.9us best) + k_gemm12 fused into layer-1 agg epilogue:
// k_agg_mlp computes s1 row per node (wave-local LDS buffer), then the
// 16 threads/node run the 13->32(ReLU)->16 MLP in-wave (no extra barrier,
// SIMD-lockstep ordering) and write hwn directly. Deletes gemm12 launch +
// 12.8MB s1 round-trip. binA/binB/k_agg byte-identical to v9.

constexpr int N_NODES = 100000;
constexpr int N_EDGES = 3200000;
constexpr int IN_CH  = 13;
constexpr int HID_CH = 32;
constexpr int LAT_CH = 16;

constexpr int NPB  = 256;                          // nodes per bucket (dst>>8)
constexpr int NBKT = (N_NODES + NPB - 1) / NPB;    // 391
constexpr int BCAP = 8960;                         // mean 8192, sd ~90 -> +8.5 sigma
constexpr int TILE = 4096;                         // edges per binA block (8/thread)

__global__ __launch_bounds__(512) void k_zero_bcur(int* __restrict__ bcur) {
    int i = threadIdx.x;
    if (i < NBKT) bcur[i] = 0;
}

// bin edges into coarse bucket regions; packed word = (dst&255)<<17 | src.
// One pass over the edge list: 8 edges/thread staged in registers (int4 x2).
__global__ __launch_bounds__(512) void k_binA(const int* __restrict__ src,
                                              const int* __restrict__ dst,
                                              int* __restrict__ bcur,
                                              int* __restrict__ buckets) {
    __shared__ int h[NBKT], st[NBKT], cur[NBKT];
    int tid = threadIdx.x;
    for (int i = tid; i < NBKT; i += 512) h[i] = 0;
    __syncthreads();
    int base8 = blockIdx.x * TILE + tid * 8;       // TILE = 512*8; groups never split
    int d[8], s[8];
    bool have = base8 < N_EDGES;
    if (have) {
        const int4* dp = (const int4*)(dst + base8);
        const int4* sp = (const int4*)(src + base8);
        int4 d0 = dp[0], d1 = dp[1];
        int4 s0 = sp[0], s1 = sp[1];
        d[0]=d0.x; d[1]=d0.y; d[2]=d0.z; d[3]=d0.w;
        d[4]=d1.x; d[5]=d1.y; d[6]=d1.z; d[7]=d1.w;
        s[0]=s0.x; s[1]=s0.y; s[2]=s0.z; s[3]=s0.w;
        s[4]=s1.x; s[5]=s1.y; s[6]=s1.z; s[7]=s1.w;
#pragma unroll
        for (int j = 0; j < 8; ++j) atomicAdd(&h[d[j] >> 8], 1);
    }
    __syncthreads();
    for (int i = tid; i < NBKT; i += 512) {
        int c = h[i];
        st[i] = c > 0 ? atomicAdd(&bcur[i], c) : 0;
        cur[i] = 0;
    }
    __syncthreads();
    if (have) {
#pragma unroll
        for (int j = 0; j < 8; ++j) {
            int b = d[j] >> 8;
            int r = atomicAdd(&cur[b], 1);
            buckets[b * BCAP + st[b] + r] = s[j] | ((d[j] & 255) << 17);
        }
    }
}

// per-bucket counting sort, fully in LDS, with fused top-scan and xn emission
// (v9 version verbatim).
__global__ __launch_bounds__(512) void k_binB(const int* __restrict__ bcur,
                                              const int* __restrict__ buckets,
                                              const float* __restrict__ x,
                                              int* __restrict__ off,
                                              float* __restrict__ dis,
                                              int* __restrict__ srcs,
                                              float* __restrict__ xn) {
    __shared__ int wbuf[BCAP];     // staged bucket words
    __shared__ int sorted_[BCAP];  // sorted src ids
    __shared__ int h[NPB], ex[NPB], curso[NPB];
    __shared__ int sv[512];        // top-level scan buffer
    __shared__ float sdis[NPB];
    int b = blockIdx.x, tid = threadIdx.x;

    // local top scan (inclusive over 512 slots, zeros beyond NBKT)
    sv[tid] = (tid < NBKT) ? bcur[tid] : 0;
    __syncthreads();
    for (int d = 1; d < 512; d <<= 1) {
        int a = sv[tid];
        int u = (tid >= d) ? sv[tid - d] : 0;
        __syncthreads();
        sv[tid] = a + u;
        __syncthreads();
    }
    int base = (b > 0) ? sv[b - 1] : 0;     // exclusive prefix for bucket b
    int cntb = bcur[b];
    if (cntb > BCAP) cntb = BCAP;
    const int* bw = buckets + b * BCAP;

    for (int i = tid; i < cntb; i += 512) wbuf[i] = bw[i];
    if (tid < NPB) h[tid] = 0;
    __syncthreads();
    for (int i = tid; i < cntb; i += 512) atomicAdd(&h[wbuf[i] >> 17], 1);
    __syncthreads();
    int node0 = b * NPB;
    if (tid < NPB) {
        int node = node0 + tid;
        float dv = rsqrtf((float)(h[tid] + 1));   // +1 self-loop
        sdis[tid] = dv;
        if (node < N_NODES) dis[node] = dv;
        ex[tid] = h[tid];
    }
    __syncthreads();
    for (int d = 1; d < NPB; d <<= 1) {    // inclusive scan over 256
        int a = 0, u = 0;
        if (tid < NPB) a = ex[tid];
        if (tid >= d && tid < NPB) u = ex[tid - d];
        __syncthreads();
        if (tid < NPB) ex[tid] = a + u;
        __syncthreads();
    }
    if (tid < NPB) {
        int excl = ex[tid] - h[tid];
        int node = node0 + tid;
        if (node < N_NODES) off[node] = base + excl;
        curso[tid] = excl;
    }
    if (b == 0 && tid == 0) off[N_NODES] = N_EDGES;
    __syncthreads();
    for (int i = tid; i < cntb; i += 512) {
        int w = wbuf[i];
        int r = atomicAdd(&curso[w >> 17], 1);
        sorted_[r] = w & 131071;
    }
    __syncthreads();
    for (int i = tid; i < cntb; i += 512) srcs[base + i] = sorted_[i];
    // fused xn emission for this bucket's nodes
    for (int i = tid; i < NPB * 16; i += 512) {
        int nl = i >> 4, c = i & 15;
        int node = node0 + nl;
        if (node < N_NODES)
            xn[node * 16 + c] = (c < IN_CH) ? x[node * IN_CH + c] * sdis[nl] : 0.f;
    }
}

// Layer-1 aggregation with FUSED MLP epilogue.
// Gather structure = k_agg v3 (4 nodes/wave, dual window). After the reduce,
// each node's s1 row (16 floats) is written to a wave-local LDS buffer; the
// same wave's 16 threads/node then compute relu(s1@W1+b1)@W2 * dis and store
// hwn directly. All LDS exchange is wave-local (nl = tid>>4 lies in this
// wave's node range) -> no barrier after the gather loop.
__global__ __launch_bounds__(256) void k_agg_mlp(const int* __restrict__ off,
                                                 const int* __restrict__ srcs,
                                                 const float* __restrict__ dis,
                                                 const float* __restrict__ vin,
                                                 const float* __restrict__ W1,
                                                 const float* __restrict__ b1,
                                                 const float* __restrict__ W2,
                                                 float* __restrict__ hwn) {
    __shared__ float sW1[IN_CH * HID_CH];     // 416 f
    __shared__ float sW2[HID_CH * LAT_CH];    // 512 f
    __shared__ float sb1[HID_CH];
    __shared__ float s1b[16][16];             // per-node s1 rows
    __shared__ float hb[16][HID_CH + 1];      // per-node hidden (pad 33)
    __shared__ float sdisb[16];
    int tid = threadIdx.x;
    for (int i = tid; i < IN_CH * HID_CH; i += 256) sW1[i] = W1[i];
    for (int i = tid; i < HID_CH * LAT_CH; i += 256) sW2[i] = W2[i];
    if (tid < HID_CH) sb1[tid] = b1[tid];
    __syncthreads();                           // weights visible to all waves

    int wave = (blockIdx.x * 256 + tid) >> 6;
    int lane = tid & 63;
    int q    = lane & 3;           // channel quad
    int esub = (lane >> 2) & 3;    // edge slot 0..3 (+4 second window)
    int nsub = lane >> 4;          // node sub-index 0..3
    int node = wave * 4 + nsub;
    bool valid = node < N_NODES;
    int beg = valid ? off[node] : 0;
    int end = valid ? off[node + 1] : 0;

    float ax = 0.f, ay = 0.f, az = 0.f, aw = 0.f;
    int k1 = beg + esub;
    int k2 = k1 + 4;
    int s1 = (k1 < end) ? srcs[k1] : -1;
    int s2 = (k2 < end) ? srcs[k2] : -1;
    for (int kb = beg; kb < end; kb += 8) {
        int kn = kb + 8 + esub;
        int sn1 = (kn < end)     ? srcs[kn]     : -1;
        int sn2 = (kn + 4 < end) ? srcs[kn + 4] : -1;
        float4 v1, v2;
        v1.x = v1.y = v1.z = v1.w = 0.f;
        v2.x = v2.y = v2.z = v2.w = 0.f;
        if (s1 >= 0) v1 = *((const float4*)(vin + (size_t)s1 * 16) + q);
        if (s2 >= 0) v2 = *((const float4*)(vin + (size_t)s2 * 16) + q);
        ax += v1.x + v2.x;
        ay += v1.y + v2.y;
        az += v1.z + v2.z;
        aw += v1.w + v2.w;
        s1 = sn1; s2 = sn2;
    }
#pragma unroll
    for (int m = 4; m <= 8; m <<= 1) {
        ax += __shfl_xor(ax, m);
        ay += __shfl_xor(ay, m);
        az += __shfl_xor(az, m);
        aw += __shfl_xor(aw, m);
    }
    int nl = ((tid >> 6) << 2) | nsub;         // node index within block, 0..15
    if (esub == 0 && valid) {
        const float4 self = *((const float4*)(vin + (size_t)node * 16) + q);
        float d = dis[node];
        float4 r;
        r.x = d * (ax + self.x);
        r.y = d * (ay + self.y);
        r.z = d * (az + self.z);
        r.w = d * (aw + self.w);
        *((float4*)&s1b[nl][q * 4]) = r;       // row stride 64B: float4-aligned
        if (q == 0) sdisb[nl] = d;
    }
    // wave-local exchange: nl range of this wave == (tid>>4) range -> no barrier
    int node_l = tid >> 4, g = tid & 15;
    int gnode = blockIdx.x * 16 + node_l;
    if (gnode < N_NODES) {
        float s[16];
#pragma unroll
        for (int k = 0; k < 16; ++k) s[k] = s1b[node_l][k];
        float h0 = sb1[g], h1 = sb1[g + 16];
#pragma unroll
        for (int k = 0; k < IN_CH; ++k) {
            h0 += s[k] * sW1[k * HID_CH + g];
            h1 += s[k] * sW1[k * HID_CH + g + 16];
        }
        hb[node_l][g]      = h0 > 0.f ? h0 : 0.f;
        hb[node_l][g + 16] = h1 > 0.f ? h1 : 0.f;
        float o = 0.f;
#pragma unroll
        for (int k = 0; k < HID_CH; ++k)
            o += hb[node_l][k] * sW2[k * LAT_CH + g];
        hwn[(size_t)gnode * 16 + g] = o * sdisb[node_l];
    }
}

// Layer-2 aggregation (k_agg v3, unchanged): 4 nodes/wave, dual window.
// outv[d*16+ch] = dis[d] * (sum_edges vin[s*16+ch] + vin[d*16+ch]) + bias
__global__ __launch_bounds__(256) void k_agg(const int* __restrict__ off,
                                             const int* __restrict__ srcs,
                                             const float* __restrict__ dis,
                                             const float* __restrict__ vin,
                                             const float* __restrict__ bias,  // may be null
                                             float* __restrict__ outv) {
    int wave = (blockIdx.x * 256 + threadIdx.x) >> 6;
    int lane = threadIdx.x & 63;
    int q    = lane & 3;
    int esub = (lane >> 2) & 3;
    int nsub = lane >> 4;
    int node = wave * 4 + nsub;
    bool valid = node < N_NODES;
    int beg = valid ? off[node] : 0;
    int end = valid ? off[node + 1] : 0;

    float ax = 0.f, ay = 0.f, az = 0.f, aw = 0.f;
    int k1 = beg + esub;
    int k2 = k1 + 4;
    int s1 = (k1 < end) ? srcs[k1] : -1;
    int s2 = (k2 < end) ? srcs[k2] : -1;
    for (int kb = beg; kb < end; kb += 8) {
        int kn = kb + 8 + esub;
        int sn1 = (kn < end)     ? srcs[kn]     : -1;
        int sn2 = (kn + 4 < end) ? srcs[kn + 4] : -1;
        float4 v1, v2;
        v1.x = v1.y = v1.z = v1.w = 0.f;
        v2.x = v2.y = v2.z = v2.w = 0.f;
        if (s1 >= 0) v1 = *((const float4*)(vin + (size_t)s1 * 16) + q);
        if (s2 >= 0) v2 = *((const float4*)(vin + (size_t)s2 * 16) + q);
        ax += v1.x + v2.x;
        ay += v1.y + v2.y;
        az += v1.z + v2.z;
        aw += v1.w + v2.w;
        s1 = sn1; s2 = sn2;
    }
#pragma unroll
    for (int m = 4; m <= 8; m <<= 1) {
        ax += __shfl_xor(ax, m);
        ay += __shfl_xor(ay, m);
        az += __shfl_xor(az, m);
        aw += __shfl_xor(aw, m);
    }
    if (esub == 0 && valid) {
        const float4 self = *((const float4*)(vin + (size_t)node * 16) + q);
        float d = dis[node];
        float4 r;
        r.x = d * (ax + self.x);
        r.y = d * (ay + self.y);
        r.z = d * (az + self.z);
        r.w = d * (aw + self.w);
        if (bias) {
            const float4 bq = ((const float4*)bias)[q];
            r.x += bq.x; r.y += bq.y; r.z += bq.z; r.w += bq.w;
        }
        *((float4*)(outv + (size_t)node * 16) + q) = r;
    }
}

extern "C" void kernel_launch(void* const* d_in, const int* in_sizes, int n_in,
                              void* d_out, int out_size, void* d_ws, size_t ws_size,
                              hipStream_t stream) {
    const float* x  = (const float*)d_in[0];
    const int*   ei = (const int*)d_in[1];
    const float* W1 = (const float*)d_in[2];
    const float* b1 = (const float*)d_in[3];
    const float* W2 = (const float*)d_in[4];
    const float* b2 = (const float*)d_in[5];
    float* out = (float*)d_out;

    const int* src = ei;
    const int* dst = ei + N_EDGES;

    // ws layout (bytes):
    //   bcur[391] @ 0 (pad 4096) | off[N+1] @ 4096 | dis[N] @ 404160
    //   srcs[E]   @ 804160 (12.8MB)
    //   buckets   @ 13604160 (391*8960*4 = 14,013,440 -> ends 27,617,600)
    //   hwn       @ 20004160 (inside buckets; written post-binB, buckets dead;
    //                          must NOT alias xn: agg_mlp reads xn, writes hwn)
    //   xn        @ 27617600 (6.4MB own region; binB writes while buckets live)
    char* ws = (char*)d_ws;
    int*   bcur    = (int*)(ws);
    int*   off     = (int*)(ws + 4096);
    float* dis     = (float*)(ws + 404160);
    int*   srcs    = (int*)(ws + 804160);
    int*   buckets = (int*)(ws + 13604160);
    float* hwn     = (float*)(ws + 20004160);
    float* xn      = (float*)(ws + 27617600);

    const int NB_A  = (N_EDGES + TILE - 1) / TILE;      // 782
    const int NB_W  = (N_NODES + 15) / 16;              // 4 nodes/wave, 4 waves/block

    k_zero_bcur<<<1,    512, 0, stream>>>(bcur);
    k_binA     <<<NB_A, 512, 0, stream>>>(src, dst, bcur, buckets);
    k_binB     <<<NBKT, 512, 0, stream>>>(bcur, buckets, x, off, dis, srcs, xn);
    k_agg_mlp  <<<NB_W, 256, 0, stream>>>(off, srcs, dis, xn, W1, b1, W2, hwn);
    k_agg      <<<NB_W, 256, 0, stream>>>(off, srcs, dis, hwn, b2, out);
}

// Round 16
// 194.093 us; speedup vs baseline: 1.1838x; 1.0596x over previous
//
#include <hip/hip_runtime.h>

// GCN 2-layer, N=100000, E=3200000, 13 -> 32 -> 16.
// v14 = v13 (205.7us best) with binA at 16 edges/thread, TILE=8192:
// per-block bucket runs double (42B -> 84B) cutting partial-line write
// amplification (measured 3x at 10.5-edge runs) toward ~2x.
// binB / agg_mlp / agg byte-identical to v13.

constexpr int N_NODES = 100000;
constexpr int N_EDGES = 3200000;
constexpr int IN_CH  = 13;
constexpr int HID_CH = 32;
constexpr int LAT_CH = 16;

constexpr int NPB  = 256;                          // nodes per bucket (dst>>8)
constexpr int NBKT = (N_NODES + NPB - 1) / NPB;    // 391
constexpr int BCAP = 8960;                         // mean 8192, sd ~90 -> +8.5 sigma
constexpr int TILE = 8192;                         // edges per binA block (16/thread)

__global__ __launch_bounds__(512) void k_zero_bcur(int* __restrict__ bcur) {
    int i = threadIdx.x;
    if (i < NBKT) bcur[i] = 0;
}

// bin edges into coarse bucket regions; packed word = (dst&255)<<17 | src.
// One pass over the edge list: 16 edges/thread staged in registers (int4 x4).
__global__ __launch_bounds__(512) void k_binA(const int* __restrict__ src,
                                              const int* __restrict__ dst,
                                              int* __restrict__ bcur,
                                              int* __restrict__ buckets) {
    __shared__ int h[NBKT], st[NBKT], cur[NBKT];
    int tid = threadIdx.x;
    for (int i = tid; i < NBKT; i += 512) h[i] = 0;
    __syncthreads();
    int base16 = blockIdx.x * TILE + tid * 16;     // TILE = 512*16; groups never split
    int d[16], s[16];
    bool have = base16 < N_EDGES;
    if (have) {
        const int4* dp = (const int4*)(dst + base16);
        const int4* sp = (const int4*)(src + base16);
#pragma unroll
        for (int g = 0; g < 4; ++g) {
            int4 dv = dp[g];
            int4 sv = sp[g];
            d[g * 4 + 0] = dv.x; d[g * 4 + 1] = dv.y;
            d[g * 4 + 2] = dv.z; d[g * 4 + 3] = dv.w;
            s[g * 4 + 0] = sv.x; s[g * 4 + 1] = sv.y;
            s[g * 4 + 2] = sv.z; s[g * 4 + 3] = sv.w;
        }
#pragma unroll
        for (int j = 0; j < 16; ++j) atomicAdd(&h[d[j] >> 8], 1);
    }
    __syncthreads();
    for (int i = tid; i < NBKT; i += 512) {
        int c = h[i];
        st[i] = c > 0 ? atomicAdd(&bcur[i], c) : 0;
        cur[i] = 0;
    }
    __syncthreads();
    if (have) {
#pragma unroll
        for (int j = 0; j < 16; ++j) {
            int b = d[j] >> 8;
            int r = atomicAdd(&cur[b], 1);
            buckets[b * BCAP + st[b] + r] = s[j] | ((d[j] & 255) << 17);
        }
    }
}

// per-bucket counting sort, fully in LDS, with fused top-scan and xn emission
// (v9 version verbatim).
__global__ __launch_bounds__(512) void k_binB(const int* __restrict__ bcur,
                                              const int* __restrict__ buckets,
                                              const float* __restrict__ x,
                                              int* __restrict__ off,
                                              float* __restrict__ dis,
                                              int* __restrict__ srcs,
                                              float* __restrict__ xn) {
    __shared__ int wbuf[BCAP];     // staged bucket words
    __shared__ int sorted_[BCAP];  // sorted src ids
    __shared__ int h[NPB], ex[NPB], curso[NPB];
    __shared__ int sv[512];        // top-level scan buffer
    __shared__ float sdis[NPB];
    int b = blockIdx.x, tid = threadIdx.x;

    // local top scan (inclusive over 512 slots, zeros beyond NBKT)
    sv[tid] = (tid < NBKT) ? bcur[tid] : 0;
    __syncthreads();
    for (int d = 1; d < 512; d <<= 1) {
        int a = sv[tid];
        int u = (tid >= d) ? sv[tid - d] : 0;
        __syncthreads();
        sv[tid] = a + u;
        __syncthreads();
    }
    int base = (b > 0) ? sv[b - 1] : 0;     // exclusive prefix for bucket b
    int cntb = bcur[b];
    if (cntb > BCAP) cntb = BCAP;
    const int* bw = buckets + b * BCAP;

    for (int i = tid; i < cntb; i += 512) wbuf[i] = bw[i];
    if (tid < NPB) h[tid] = 0;
    __syncthreads();
    for (int i = tid; i < cntb; i += 512) atomicAdd(&h[wbuf[i] >> 17], 1);
    __syncthreads();
    int node0 = b * NPB;
    if (tid < NPB) {
        int node = node0 + tid;
        float dv = rsqrtf((float)(h[tid] + 1));   // +1 self-loop
        sdis[tid] = dv;
        if (node < N_NODES) dis[node] = dv;
        ex[tid] = h[tid];
    }
    __syncthreads();
    for (int d = 1; d < NPB; d <<= 1) {    // inclusive scan over 256
        int a = 0, u = 0;
        if (tid < NPB) a = ex[tid];
        if (tid >= d && tid < NPB) u = ex[tid - d];
        __syncthreads();
        if (tid < NPB) ex[tid] = a + u;
        __syncthreads();
    }
    if (tid < NPB) {
        int excl = ex[tid] - h[tid];
        int node = node0 + tid;
        if (node < N_NODES) off[node] = base + excl;
        curso[tid] = excl;
    }
    if (b == 0 && tid == 0) off[N_NODES] = N_EDGES;
    __syncthreads();
    for (int i = tid; i < cntb; i += 512) {
        int w = wbuf[i];
        int r = atomicAdd(&curso[w >> 17], 1);
        sorted_[r] = w & 131071;
    }
    __syncthreads();
    for (int i = tid; i < cntb; i += 512) srcs[base + i] = sorted_[i];
    // fused xn emission for this bucket's nodes
    for (int i = tid; i < NPB * 16; i += 512) {
        int nl = i >> 4, c = i & 15;
        int node = node0 + nl;
        if (node < N_NODES)
            xn[node * 16 + c] = (c < IN_CH) ? x[node * IN_CH + c] * sdis[nl] : 0.f;
    }
}

// Layer-1 aggregation with FUSED MLP epilogue (v13 verbatim).
__global__ __launch_bounds__(256) void k_agg_mlp(const int* __restrict__ off,
                                                 const int* __restrict__ srcs,
                                                 const float* __restrict__ dis,
                                                 const float* __restrict__ vin,
                                                 const float* __restrict__ W1,
                                                 const float* __restrict__ b1,
                                                 const float* __restrict__ W2,
                                                 float* __restrict__ hwn) {
    __shared__ float sW1[IN_CH * HID_CH];     // 416 f
    __shared__ float sW2[HID_CH * LAT_CH];    // 512 f
    __shared__ float sb1[HID_CH];
    __shared__ float s1b[16][16];             // per-node s1 rows
    __shared__ float hb[16][HID_CH + 1];      // per-node hidden (pad 33)
    __shared__ float sdisb[16];
    int tid = threadIdx.x;
    for (int i = tid; i < IN_CH * HID_CH; i += 256) sW1[i] = W1[i];
    for (int i = tid; i < HID_CH * LAT_CH; i += 256) sW2[i] = W2[i];
    if (tid < HID_CH) sb1[tid] = b1[tid];
    __syncthreads();                           // weights visible to all waves

    int wave = (blockIdx.x * 256 + tid) >> 6;
    int lane = tid & 63;
    int q    = lane & 3;           // channel quad
    int esub = (lane >> 2) & 3;    // edge slot 0..3 (+4 second window)
    int nsub = lane >> 4;          // node sub-index 0..3
    int node = wave * 4 + nsub;
    bool valid = node < N_NODES;
    int beg = valid ? off[node] : 0;
    int end = valid ? off[node + 1] : 0;

    float ax = 0.f, ay = 0.f, az = 0.f, aw = 0.f;
    int k1 = beg + esub;
    int k2 = k1 + 4;
    int s1 = (k1 < end) ? srcs[k1] : -1;
    int s2 = (k2 < end) ? srcs[k2] : -1;
    for (int kb = beg; kb < end; kb += 8) {
        int kn = kb + 8 + esub;
        int sn1 = (kn < end)     ? srcs[kn]     : -1;
        int sn2 = (kn + 4 < end) ? srcs[kn + 4] : -1;
        float4 v1, v2;
        v1.x = v1.y = v1.z = v1.w = 0.f;
        v2.x = v2.y = v2.z = v2.w = 0.f;
        if (s1 >= 0) v1 = *((const float4*)(vin + (size_t)s1 * 16) + q);
        if (s2 >= 0) v2 = *((const float4*)(vin + (size_t)s2 * 16) + q);
        ax += v1.x + v2.x;
        ay += v1.y + v2.y;
        az += v1.z + v2.z;
        aw += v1.w + v2.w;
        s1 = sn1; s2 = sn2;
    }
#pragma unroll
    for (int m = 4; m <= 8; m <<= 1) {
        ax += __shfl_xor(ax, m);
        ay += __shfl_xor(ay, m);
        az += __shfl_xor(az, m);
        aw += __shfl_xor(aw, m);
    }
    int nl = ((tid >> 6) << 2) | nsub;         // node index within block, 0..15
    if (esub == 0 && valid) {
        const float4 self = *((const float4*)(vin + (size_t)node * 16) + q);
        float d = dis[node];
        float4 r;
        r.x = d * (ax + self.x);
        r.y = d * (ay + self.y);
        r.z = d * (az + self.z);
        r.w = d * (aw + self.w);
        *((float4*)&s1b[nl][q * 4]) = r;       // row stride 64B: float4-aligned
        if (q == 0) sdisb[nl] = d;
    }
    // wave-local exchange: nl range of this wave == (tid>>4) range -> no barrier
    int node_l = tid >> 4, g = tid & 15;
    int gnode = blockIdx.x * 16 + node_l;
    if (gnode < N_NODES) {
        float s[16];
#pragma unroll
        for (int k = 0; k < 16; ++k) s[k] = s1b[node_l][k];
        float h0 = sb1[g], h1 = sb1[g + 16];
#pragma unroll
        for (int k = 0; k < IN_CH; ++k) {
            h0 += s[k] * sW1[k * HID_CH + g];
            h1 += s[k] * sW1[k * HID_CH + g + 16];
        }
        hb[node_l][g]      = h0 > 0.f ? h0 : 0.f;
        hb[node_l][g + 16] = h1 > 0.f ? h1 : 0.f;
        float o = 0.f;
#pragma unroll
        for (int k = 0; k < HID_CH; ++k)
            o += hb[node_l][k] * sW2[k * LAT_CH + g];
        hwn[(size_t)gnode * 16 + g] = o * sdisb[node_l];
    }
}

// Layer-2 aggregation (k_agg v3, unchanged): 4 nodes/wave, dual window.
// outv[d*16+ch] = dis[d] * (sum_edges vin[s*16+ch] + vin[d*16+ch]) + bias
__global__ __launch_bounds__(256) void k_agg(const int* __restrict__ off,
                                             const int* __restrict__ srcs,
                                             const float* __restrict__ dis,
                                             const float* __restrict__ vin,
                                             const float* __restrict__ bias,  // may be null
                                             float* __restrict__ outv) {
    int wave = (blockIdx.x * 256 + threadIdx.x) >> 6;
    int lane = threadIdx.x & 63;
    int q    = lane & 3;
    int esub = (lane >> 2) & 3;
    int nsub = lane >> 4;
    int node = wave * 4 + nsub;
    bool valid = node < N_NODES;
    int beg = valid ? off[node] : 0;
    int end = valid ? off[node + 1] : 0;

    float ax = 0.f, ay = 0.f, az = 0.f, aw = 0.f;
    int k1 = beg + esub;
    int k2 = k1 + 4;
    int s1 = (k1 < end) ? srcs[k1] : -1;
    int s2 = (k2 < end) ? srcs[k2] : -1;
    for (int kb = beg; kb < end; kb += 8) {
        int kn = kb + 8 + esub;
        int sn1 = (kn < end)     ? srcs[kn]     : -1;
        int sn2 = (kn + 4 < end) ? srcs[kn + 4] : -1;
        float4 v1, v2;
        v1.x = v1.y = v1.z = v1.w = 0.f;
        v2.x = v2.y = v2.z = v2.w = 0.f;
        if (s1 >= 0) v1 = *((const float4*)(vin + (size_t)s1 * 16) + q);
        if (s2 >= 0) v2 = *((const float4*)(vin + (size_t)s2 * 16) + q);
        ax += v1.x + v2.x;
        ay += v1.y + v2.y;
        az += v1.z + v2.z;
        aw += v1.w + v2.w;
        s1 = sn1; s2 = sn2;
    }
#pragma unroll
    for (int m = 4; m <= 8; m <<= 1) {
        ax += __shfl_xor(ax, m);
        ay += __shfl_xor(ay, m);
        az += __shfl_xor(az, m);
        aw += __shfl_xor(aw, m);
    }
    if (esub == 0 && valid) {
        const float4 self = *((const float4*)(vin + (size_t)node * 16) + q);
        float d = dis[node];
        float4 r;
        r.x = d * (ax + self.x);
        r.y = d * (ay + self.y);
        r.z = d * (az + self.z);
        r.w = d * (aw + self.w);
        if (bias) {
            const float4 bq = ((const float4*)bias)[q];
            r.x += bq.x; r.y += bq.y; r.z += bq.z; r.w += bq.w;
        }
        *((float4*)(outv + (size_t)node * 16) + q) = r;
    }
}

extern "C" void kernel_launch(void* const* d_in, const int* in_sizes, int n_in,
                              void* d_out, int out_size, void* d_ws, size_t ws_size,
                              hipStream_t stream) {
    const float* x  = (const float*)d_in[0];
    const int*   ei = (const int*)d_in[1];
    const float* W1 = (const float*)d_in[2];
    const float* b1 = (const float*)d_in[3];
    const float* W2 = (const float*)d_in[4];
    const float* b2 = (const float*)d_in[5];
    float* out = (float*)d_out;

    const int* src = ei;
    const int* dst = ei + N_EDGES;

    // ws layout (bytes):
    //   bcur[391] @ 0 (pad 4096) | off[N+1] @ 4096 | dis[N] @ 404160
    //   srcs[E]   @ 804160 (12.8MB)
    //   buckets   @ 13604160 (391*8960*4 = 14,013,440 -> ends 27,617,600)
    //   hwn       @ 20004160 (inside buckets; written post-binB, buckets dead;
    //                          must NOT alias xn: agg_mlp reads xn, writes hwn)
    //   xn        @ 27617600 (6.4MB own region; binB writes while buckets live)
    char* ws = (char*)d_ws;
    int*   bcur    = (int*)(ws);
    int*   off     = (int*)(ws + 4096);
    float* dis     = (float*)(ws + 404160);
    int*   srcs    = (int*)(ws + 804160);
    int*   buckets = (int*)(ws + 13604160);
    float* hwn     = (float*)(ws + 20004160);
    float* xn      = (float*)(ws + 27617600);

    const int NB_A  = (N_EDGES + TILE - 1) / TILE;      // 391
    const int NB_W  = (N_NODES + 15) / 16;              // 4 nodes/wave, 4 waves/block

    k_zero_bcur<<<1,    512, 0, stream>>>(bcur);
    k_binA     <<<NB_A, 512, 0, stream>>>(src, dst, bcur, buckets);
    k_binB     <<<NBKT, 512, 0, stream>>>(bcur, buckets, x, off, dis, srcs, xn);
    k_agg_mlp  <<<NB_W, 256, 0, stream>>>(off, srcs, dis, xn, W1, b1, W2, hwn);
    k_agg      <<<NB_W, 256, 0, stream>>>(off, srcs, dis, hwn, b2, out);
}

// Round 17
// 193.891 us; speedup vs baseline: 1.1850x; 1.0010x over previous
//
#include <hip/hip_runtime.h>

// GCN 2-layer, N=100000, E=3200000, 13 -> 32 -> 16.
// v15 = v14 (194.1us best) with binB at 1024 threads/block: LDS (77KB) allows
// 2 blocks/CU at either width; 1024thr doubles resident waves 16->32/CU (100%
// occupancy) and halves per-block strided-loop iterations.
// binA / agg_mlp / agg byte-identical to v14.

constexpr int N_NODES = 100000;
constexpr int N_EDGES = 3200000;
constexpr int IN_CH  = 13;
constexpr int HID_CH = 32;
constexpr int LAT_CH = 16;

constexpr int NPB  = 256;                          // nodes per bucket (dst>>8)
constexpr int NBKT = (N_NODES + NPB - 1) / NPB;    // 391
constexpr int BCAP = 8960;                         // mean 8192, sd ~90 -> +8.5 sigma
constexpr int TILE = 8192;                         // edges per binA block (16/thread)

__global__ __launch_bounds__(512) void k_zero_bcur(int* __restrict__ bcur) {
    int i = threadIdx.x;
    if (i < NBKT) bcur[i] = 0;
}

// bin edges into coarse bucket regions; packed word = (dst&255)<<17 | src.
// One pass over the edge list: 16 edges/thread staged in registers (int4 x4).
__global__ __launch_bounds__(512) void k_binA(const int* __restrict__ src,
                                              const int* __restrict__ dst,
                                              int* __restrict__ bcur,
                                              int* __restrict__ buckets) {
    __shared__ int h[NBKT], st[NBKT], cur[NBKT];
    int tid = threadIdx.x;
    for (int i = tid; i < NBKT; i += 512) h[i] = 0;
    __syncthreads();
    int base16 = blockIdx.x * TILE + tid * 16;     // TILE = 512*16; groups never split
    int d[16], s[16];
    bool have = base16 < N_EDGES;
    if (have) {
        const int4* dp = (const int4*)(dst + base16);
        const int4* sp = (const int4*)(src + base16);
#pragma unroll
        for (int g = 0; g < 4; ++g) {
            int4 dv = dp[g];
            int4 sv = sp[g];
            d[g * 4 + 0] = dv.x; d[g * 4 + 1] = dv.y;
            d[g * 4 + 2] = dv.z; d[g * 4 + 3] = dv.w;
            s[g * 4 + 0] = sv.x; s[g * 4 + 1] = sv.y;
            s[g * 4 + 2] = sv.z; s[g * 4 + 3] = sv.w;
        }
#pragma unroll
        for (int j = 0; j < 16; ++j) atomicAdd(&h[d[j] >> 8], 1);
    }
    __syncthreads();
    for (int i = tid; i < NBKT; i += 512) {
        int c = h[i];
        st[i] = c > 0 ? atomicAdd(&bcur[i], c) : 0;
        cur[i] = 0;
    }
    __syncthreads();
    if (have) {
#pragma unroll
        for (int j = 0; j < 16; ++j) {
            int b = d[j] >> 8;
            int r = atomicAdd(&cur[b], 1);
            buckets[b * BCAP + st[b] + r] = s[j] | ((d[j] & 255) << 17);
        }
    }
}

// per-bucket counting sort, fully in LDS (v9 body at 1024 threads):
// top-scan confined to tid<512 (all threads hit barriers); strided loops 1024.
__global__ __launch_bounds__(1024) void k_binB(const int* __restrict__ bcur,
                                               const int* __restrict__ buckets,
                                               const float* __restrict__ x,
                                               int* __restrict__ off,
                                               float* __restrict__ dis,
                                               int* __restrict__ srcs,
                                               float* __restrict__ xn) {
    __shared__ int wbuf[BCAP];     // staged bucket words
    __shared__ int sorted_[BCAP];  // sorted src ids
    __shared__ int h[NPB], ex[NPB], curso[NPB];
    __shared__ int sv[512];        // top-level scan buffer
    __shared__ float sdis[NPB];
    int b = blockIdx.x, tid = threadIdx.x;

    // local top scan (inclusive over 512 slots, zeros beyond NBKT)
    if (tid < 512) sv[tid] = (tid < NBKT) ? bcur[tid] : 0;
    __syncthreads();
    for (int d = 1; d < 512; d <<= 1) {
        int a = 0, u = 0;
        if (tid < 512) {
            a = sv[tid];
            u = (tid >= d) ? sv[tid - d] : 0;
        }
        __syncthreads();
        if (tid < 512) sv[tid] = a + u;
        __syncthreads();
    }
    int base = (b > 0) ? sv[b - 1] : 0;     // exclusive prefix for bucket b
    int cntb = bcur[b];
    if (cntb > BCAP) cntb = BCAP;
    const int* bw = buckets + b * BCAP;

    for (int i = tid; i < cntb; i += 1024) wbuf[i] = bw[i];
    if (tid < NPB) h[tid] = 0;
    __syncthreads();
    for (int i = tid; i < cntb; i += 1024) atomicAdd(&h[wbuf[i] >> 17], 1);
    __syncthreads();
    int node0 = b * NPB;
    if (tid < NPB) {
        int node = node0 + tid;
        float dv = rsqrtf((float)(h[tid] + 1));   // +1 self-loop
        sdis[tid] = dv;
        if (node < N_NODES) dis[node] = dv;
        ex[tid] = h[tid];
    }
    __syncthreads();
    for (int d = 1; d < NPB; d <<= 1) {    // inclusive scan over 256
        int a = 0, u = 0;
        if (tid < NPB) a = ex[tid];
        if (tid >= d && tid < NPB) u = ex[tid - d];
        __syncthreads();
        if (tid < NPB) ex[tid] = a + u;
        __syncthreads();
    }
    if (tid < NPB) {
        int excl = ex[tid] - h[tid];
        int node = node0 + tid;
        if (node < N_NODES) off[node] = base + excl;
        curso[tid] = excl;
    }
    if (b == 0 && tid == 0) off[N_NODES] = N_EDGES;
    __syncthreads();
    for (int i = tid; i < cntb; i += 1024) {
        int w = wbuf[i];
        int r = atomicAdd(&curso[w >> 17], 1);
        sorted_[r] = w & 131071;
    }
    __syncthreads();
    for (int i = tid; i < cntb; i += 1024) srcs[base + i] = sorted_[i];
    // fused xn emission for this bucket's nodes
    for (int i = tid; i < NPB * 16; i += 1024) {
        int nl = i >> 4, c = i & 15;
        int node = node0 + nl;
        if (node < N_NODES)
            xn[node * 16 + c] = (c < IN_CH) ? x[node * IN_CH + c] * sdis[nl] : 0.f;
    }
}

// Layer-1 aggregation with FUSED MLP epilogue (v13 verbatim).
__global__ __launch_bounds__(256) void k_agg_mlp(const int* __restrict__ off,
                                                 const int* __restrict__ srcs,
                                                 const float* __restrict__ dis,
                                                 const float* __restrict__ vin,
                                                 const float* __restrict__ W1,
                                                 const float* __restrict__ b1,
                                                 const float* __restrict__ W2,
                                                 float* __restrict__ hwn) {
    __shared__ float sW1[IN_CH * HID_CH];     // 416 f
    __shared__ float sW2[HID_CH * LAT_CH];    // 512 f
    __shared__ float sb1[HID_CH];
    __shared__ float s1b[16][16];             // per-node s1 rows
    __shared__ float hb[16][HID_CH + 1];      // per-node hidden (pad 33)
    __shared__ float sdisb[16];
    int tid = threadIdx.x;
    for (int i = tid; i < IN_CH * HID_CH; i += 256) sW1[i] = W1[i];
    for (int i = tid; i < HID_CH * LAT_CH; i += 256) sW2[i] = W2[i];
    if (tid < HID_CH) sb1[tid] = b1[tid];
    __syncthreads();                           // weights visible to all waves

    int wave = (blockIdx.x * 256 + tid) >> 6;
    int lane = tid & 63;
    int q    = lane & 3;           // channel quad
    int esub = (lane >> 2) & 3;    // edge slot 0..3 (+4 second window)
    int nsub = lane >> 4;          // node sub-index 0..3
    int node = wave * 4 + nsub;
    bool valid = node < N_NODES;
    int beg = valid ? off[node] : 0;
    int end = valid ? off[node + 1] : 0;

    float ax = 0.f, ay = 0.f, az = 0.f, aw = 0.f;
    int k1 = beg + esub;
    int k2 = k1 + 4;
    int s1 = (k1 < end) ? srcs[k1] : -1;
    int s2 = (k2 < end) ? srcs[k2] : -1;
    for (int kb = beg; kb < end; kb += 8) {
        int kn = kb + 8 + esub;
        int sn1 = (kn < end)     ? srcs[kn]     : -1;
        int sn2 = (kn + 4 < end) ? srcs[kn + 4] : -1;
        float4 v1, v2;
        v1.x = v1.y = v1.z = v1.w = 0.f;
        v2.x = v2.y = v2.z = v2.w = 0.f;
        if (s1 >= 0) v1 = *((const float4*)(vin + (size_t)s1 * 16) + q);
        if (s2 >= 0) v2 = *((const float4*)(vin + (size_t)s2 * 16) + q);
        ax += v1.x + v2.x;
        ay += v1.y + v2.y;
        az += v1.z + v2.z;
        aw += v1.w + v2.w;
        s1 = sn1; s2 = sn2;
    }
#pragma unroll
    for (int m = 4; m <= 8; m <<= 1) {
        ax += __shfl_xor(ax, m);
        ay += __shfl_xor(ay, m);
        az += __shfl_xor(az, m);
        aw += __shfl_xor(aw, m);
    }
    int nl = ((tid >> 6) << 2) | nsub;         // node index within block, 0..15
    if (esub == 0 && valid) {
        const float4 self = *((const float4*)(vin + (size_t)node * 16) + q);
        float d = dis[node];
        float4 r;
        r.x = d * (ax + self.x);
        r.y = d * (ay + self.y);
        r.z = d * (az + self.z);
        r.w = d * (aw + self.w);
        *((float4*)&s1b[nl][q * 4]) = r;       // row stride 64B: float4-aligned
        if (q == 0) sdisb[nl] = d;
    }
    // wave-local exchange: nl range of this wave == (tid>>4) range -> no barrier
    int node_l = tid >> 4, g = tid & 15;
    int gnode = blockIdx.x * 16 + node_l;
    if (gnode < N_NODES) {
        float s[16];
#pragma unroll
        for (int k = 0; k < 16; ++k) s[k] = s1b[node_l][k];
        float h0 = sb1[g], h1 = sb1[g + 16];
#pragma unroll
        for (int k = 0; k < IN_CH; ++k) {
            h0 += s[k] * sW1[k * HID_CH + g];
            h1 += s[k] * sW1[k * HID_CH + g + 16];
        }
        hb[node_l][g]      = h0 > 0.f ? h0 : 0.f;
        hb[node_l][g + 16] = h1 > 0.f ? h1 : 0.f;
        float o = 0.f;
#pragma unroll
        for (int k = 0; k < HID_CH; ++k)
            o += hb[node_l][k] * sW2[k * LAT_CH + g];
        hwn[(size_t)gnode * 16 + g] = o * sdisb[node_l];
    }
}

// Layer-2 aggregation (k_agg v3, unchanged): 4 nodes/wave, dual window.
// outv[d*16+ch] = dis[d] * (sum_edges vin[s*16+ch] + vin[d*16+ch]) + bias
__global__ __launch_bounds__(256) void k_agg(const int* __restrict__ off,
                                             const int* __restrict__ srcs,
                                             const float* __restrict__ dis,
                                             const float* __restrict__ vin,
                                             const float* __restrict__ bias,  // may be null
                                             float* __restrict__ outv) {
    int wave = (blockIdx.x * 256 + threadIdx.x) >> 6;
    int lane = threadIdx.x & 63;
    int q    = lane & 3;
    int esub = (lane >> 2) & 3;
    int nsub = lane >> 4;
    int node = wave * 4 + nsub;
    bool valid = node < N_NODES;
    int beg = valid ? off[node] : 0;
    int end = valid ? off[node + 1] : 0;

    float ax = 0.f, ay = 0.f, az = 0.f, aw = 0.f;
    int k1 = beg + esub;
    int k2 = k1 + 4;
    int s1 = (k1 < end) ? srcs[k1] : -1;
    int s2 = (k2 < end) ? srcs[k2] : -1;
    for (int kb = beg; kb < end; kb += 8) {
        int kn = kb + 8 + esub;
        int sn1 = (kn < end)     ? srcs[kn]     : -1;
        int sn2 = (kn + 4 < end) ? srcs[kn + 4] : -1;
        float4 v1, v2;
        v1.x = v1.y = v1.z = v1.w = 0.f;
        v2.x = v2.y = v2.z = v2.w = 0.f;
        if (s1 >= 0) v1 = *((const float4*)(vin + (size_t)s1 * 16) + q);
        if (s2 >= 0) v2 = *((const float4*)(vin + (size_t)s2 * 16) + q);
        ax += v1.x + v2.x;
        ay += v1.y + v2.y;
        az += v1.z + v2.z;
        aw += v1.w + v2.w;
        s1 = sn1; s2 = sn2;
    }
#pragma unroll
    for (int m = 4; m <= 8; m <<= 1) {
        ax += __shfl_xor(ax, m);
        ay += __shfl_xor(ay, m);
        az += __shfl_xor(az, m);
        aw += __shfl_xor(aw, m);
    }
    if (esub == 0 && valid) {
        const float4 self = *((const float4*)(vin + (size_t)node * 16) + q);
        float d = dis[node];
        float4 r;
        r.x = d * (ax + self.x);
        r.y = d * (ay + self.y);
        r.z = d * (az + self.z);
        r.w = d * (aw + self.w);
        if (bias) {
            const float4 bq = ((const float4*)bias)[q];
            r.x += bq.x; r.y += bq.y; r.z += bq.z; r.w += bq.w;
        }
        *((float4*)(outv + (size_t)node * 16) + q) = r;
    }
}

extern "C" void kernel_launch(void* const* d_in, const int* in_sizes, int n_in,
                              void* d_out, int out_size, void* d_ws, size_t ws_size,
                              hipStream_t stream) {
    const float* x  = (const float*)d_in[0];
    const int*   ei = (const int*)d_in[1];
    const float* W1 = (const float*)d_in[2];
    const float* b1 = (const float*)d_in[3];
    const float* W2 = (const float*)d_in[4];
    const float* b2 = (const float*)d_in[5];
    float* out = (float*)d_out;

    const int* src = ei;
    const int* dst = ei + N_EDGES;

    // ws layout (bytes):
    //   bcur[391] @ 0 (pad 4096) | off[N+1] @ 4096 | dis[N] @ 404160
    //   srcs[E]   @ 804160 (12.8MB)
    //   buckets   @ 13604160 (391*8960*4 = 14,013,440 -> ends 27,617,600)
    //   hwn       @ 20004160 (inside buckets; written post-binB, buckets dead;
    //                          must NOT alias xn: agg_mlp reads xn, writes hwn)
    //   xn        @ 27617600 (6.4MB own region; binB writes while buckets live)
    char* ws = (char*)d_ws;
    int*   bcur    = (int*)(ws);
    int*   off     = (int*)(ws + 4096);
    float* dis     = (float*)(ws + 404160);
    int*   srcs    = (int*)(ws + 804160);
    int*   buckets = (int*)(ws + 13604160);
    float* hwn     = (float*)(ws + 20004160);
    float* xn      = (float*)(ws + 27617600);

    const int NB_A  = (N_EDGES + TILE - 1) / TILE;      // 391
    const int NB_W  = (N_NODES + 15) / 16;              // 4 nodes/wave, 4 waves/block

    k_zero_bcur<<<1,    512, 0, stream>>>(bcur);
    k_binA     <<<NB_A, 512, 0, stream>>>(src, dst, bcur, buckets);
    k_binB     <<<NBKT, 1024, 0, stream>>>(bcur, buckets, x, off, dis, srcs, xn);
    k_agg_mlp  <<<NB_W, 256, 0, stream>>>(off, srcs, dis, xn, W1, b1, W2, hwn);
    k_agg      <<<NB_W, 256, 0, stream>>>(off, srcs, dis, hwn, b2, out);
}